// Round 15
// baseline (215.860 us; speedup 1.0000x reference)
//
#include <hip/hip_runtime.h>

// Problem constants
#define NEXP   8
#define L1DIM  3072
#define BATCH  32768
#define SQCORR (127.0f / 128.0f)
#define CHUNK  256                    // floats per row per K-step
#define NCHUNK (L1DIM / CHUNK)        // 12

// Workspace layout (int units)
#define NBLK_SORT   (BATCH / 256)           // 128
#define WS_HIST     0                       // [128*8] per-block expert counts
#define WS_OFF      (NBLK_SORT * NEXP)      // [128*8] absolute write offsets
#define WS_COUNT    (2 * NBLK_SORT * NEXP)  // [8] total per-expert counts
#define WS_SORTED   (WS_COUNT + 16)         // [8*BATCH]
#define BLK_PER_E   (BATCH / 16)            // 2048
#define NBLK_MAIN   (NEXP * BLK_PER_E)      // 16384 (most early-exit)

// Pass 1: per-block expert histogram (LDS atomics, 8 global writes/block).
__global__ void hist_k(const int* __restrict__ routing, int* ws) {
    __shared__ int h[NEXP];
    if (threadIdx.x < NEXP) h[threadIdx.x] = 0;
    __syncthreads();
    int i = blockIdx.x * 256 + threadIdx.x;
    atomicAdd(&h[routing[i]], 1);
    __syncthreads();
    if (threadIdx.x < NEXP)
        ws[WS_HIST + blockIdx.x * NEXP + threadIdx.x] = h[threadIdx.x];
}

// Pass 2: exclusive scan of 128 block-histograms per expert (1 block,
// 128 threads = 2 waves, shfl_up intra-wave + LDS cross-wave fixup).
// Emits absolute write offsets (seg base e*BATCH included) and totals.
__global__ void scan_k(int* ws) {
    const int t = threadIdx.x;            // t = sort-block id 0..127
    const int wid = t >> 6, lane = t & 63;
    int h[NEXP], s[NEXP];
    #pragma unroll
    for (int e = 0; e < NEXP; ++e) { h[e] = ws[WS_HIST + t * NEXP + e]; s[e] = h[e]; }
    #pragma unroll
    for (int d = 1; d < 64; d <<= 1) {
        #pragma unroll
        for (int e = 0; e < NEXP; ++e) {
            int u = __shfl_up(s[e], d, 64);
            if (lane >= d) s[e] += u;
        }
    }
    __shared__ int w0[NEXP];
    if (wid == 0 && lane == 63) {
        #pragma unroll
        for (int e = 0; e < NEXP; ++e) w0[e] = s[e];
    }
    __syncthreads();
    if (wid == 1) {
        #pragma unroll
        for (int e = 0; e < NEXP; ++e) s[e] += w0[e];
    }
    #pragma unroll
    for (int e = 0; e < NEXP; ++e)
        ws[WS_OFF + t * NEXP + e] = e * BATCH + (s[e] - h[e]);
    if (t == 127) {
        #pragma unroll
        for (int e = 0; e < NEXP; ++e) ws[WS_COUNT + e] = s[e];
    }
}

// Pass 3: STABLE scatter -> expert segments ASCENDING by row index.
// (wave ballot rank + cross-wave LDS hist; zero global atomics)
__global__ void scatter_k(const int* __restrict__ routing, int* ws) {
    __shared__ int wh[4][NEXP];
    const int t = threadIdx.x, wid = t >> 6, lane = t & 63;
    if (t < 32) ((int*)wh)[t] = 0;
    __syncthreads();
    const int i = blockIdx.x * 256 + t;
    const int my_e = routing[i];
    int lower = 0;
    #pragma unroll
    for (int e = 0; e < NEXP; ++e) {
        unsigned long long m = __ballot(my_e == e);
        if (my_e == e) lower = (int)__popcll(m & ((1ULL << lane) - 1ULL));
        if (m && lane == (__ffsll((long long)m) - 1)) wh[wid][e] = (int)__popcll(m);
    }
    __syncthreads();
    int rank = lower;
    #pragma unroll
    for (int w = 0; w < 3; ++w) if (w < wid) rank += wh[w][my_e];
    ws[WS_SORTED + ws[WS_OFF + blockIdx.x * NEXP + my_e] + rank] = i;
}

// async 16B global -> LDS copy (per-lane global src, wave-linear LDS dest)
__device__ __forceinline__ void lds_cp16(void* lds, const void* g) {
    __builtin_amdgcn_global_load_lds(
        (const __attribute__((address_space(1))) void*)g,
        (__attribute__((address_space(3))) void*)lds, 16, 0, 0);
}

// Main fused kernel — EXACT R12 structure (o-split, same-chunk wv, 3-deep
// gll x pipeline, per-chunk vmcnt(4)+barrier) with __launch_bounds__(256,1)
// (R13 showed (256,3) caps VGPR at 84 -> spill; (256,1) -> no cap pressure;
// LDS 49KB remains the occupancy binder at 3 blocks/CU).
// NEW INPUT PROPERTY under test: segments are ascending by row index, so
// co-dispatched blocks sweep contiguous x windows (DRAM page locality).
__global__ __launch_bounds__(256, 1) void moe_main_k(
        const float* __restrict__ x, const int* __restrict__ ws,
        const float* __restrict__ w1, const float* __restrict__ b1,
        const float* __restrict__ w2, const float* __restrict__ b2,
        const float* __restrict__ w3, const float* __restrict__ b3,
        float* __restrict__ out) {
    __shared__ float xs[3][16][CHUNK];    // 48 KB
    __shared__ float tot[4][64];          // 49 KB total -> 3 blocks/CU

    const int e   = blockIdx.x % NEXP;
    const int b16 = (blockIdx.x / NEXP) * 16;
    const int n   = ws[WS_COUNT + e];
    if (b16 >= n) return;    // uniform: all 4 waves exit before any barrier

    const int tid  = threadIdx.x;
    const int wid  = tid >> 6;
    const int lane = tid & 63;
    const int r0   = wid * 4;             // rows this wave STAGES
    const int loff = lane * 4;

    int rows[4];
    const float* xp[4];
    #pragma unroll
    for (int q = 0; q < 4; ++q) {
        int s = b16 + r0 + q;
        rows[q] = (s < n) ? ws[WS_SORTED + e * BATCH + s] : -1;
        int r = rows[q] < 0 ? 0 : rows[q];
        xp[q] = x + (size_t)r * L1DIM;
    }
    // this wave's 4 output rows of w1[e]: o = wid*4 + oo
    const float* w1e = w1 + ((size_t)e * 16 + wid * 4) * L1DIM + loff;

    auto issue_x = [&](int t) {
        const int b = t % 3;
        const int koff = t * CHUNK + loff;
        #pragma unroll
        for (int q = 0; q < 4; ++q)
            lds_cp16(&xs[b][r0 + q][loff], xp[q] + koff);
    };

    float acc[64];                        // acc[r*4 + oo]
    #pragma unroll
    for (int k = 0; k < 64; ++k) acc[k] = 0.0f;

    issue_x(0);
    issue_x(1);

    #pragma unroll 1
    for (int t = 0; t < NCHUNK; ++t) {
        const int xb = t % 3;
        // own x(t) drained (keep x(t+1) in flight), then block-wide visible
        asm volatile("s_waitcnt vmcnt(4)" ::: "memory");
        __builtin_amdgcn_s_barrier();
        __builtin_amdgcn_sched_barrier(0);

        // this wave's 4 w1 vectors for chunk t (only o-slice it owns)
        float4 wv[4];
        #pragma unroll
        for (int oo = 0; oo < 4; ++oo)
            wv[oo] = *(const float4*)(w1e + t * CHUNK + (size_t)oo * L1DIM);

        __builtin_amdgcn_sched_barrier(0);
        if (t + 2 < NCHUNK) issue_x(t + 2);
        __builtin_amdgcn_sched_barrier(0);

        // all 16 block rows x this wave's 4 outputs
        #pragma unroll
        for (int rg = 0; rg < 4; ++rg) {
            float4 xv[4];
            #pragma unroll
            for (int rr = 0; rr < 4; ++rr)
                xv[rr] = *(const float4*)&xs[xb][rg * 4 + rr][loff];
            #pragma unroll
            for (int oo = 0; oo < 4; ++oo) {
                #pragma unroll
                for (int rr = 0; rr < 4; ++rr) {
                    const int v = (rg * 4 + rr) * 4 + oo;
                    float a = acc[v];
                    a = fmaf(xv[rr].x, wv[oo].x, a);
                    a = fmaf(xv[rr].y, wv[oo].y, a);
                    a = fmaf(xv[rr].z, wv[oo].z, a);
                    a = fmaf(xv[rr].w, wv[oo].w, a);
                    acc[v] = a;
                }
            }
        }
    }

    // Reduce-scatter butterfly: lane l ends with total of value idx l,
    // where idx v = block_row(v>>2)*4 + oo; this wave's o = wid*4+oo.
    #pragma unroll
    for (int s = 0; s < 6; ++s) {
        const int mask = 32 >> s;
        const bool hi = (lane & mask) != 0;
        #pragma unroll
        for (int k = 0; k < 32; ++k) {
            if (k >= mask) break;
            float give = hi ? acc[k] : acc[k + mask];
            float got  = __shfl_xor(give, mask, 64);
            float keep = hi ? acc[k + mask] : acc[k];
            acc[k] = keep + got;
        }
    }

    tot[wid][lane] = acc[0];   // tot[w][R*4+oo] = out (R, o=w*4+oo)
    __syncthreads();

    // Epilogue: wave wid handles block rows wid*4+q (== its rows[q]).
    const int q = lane >> 4;
    const int j = lane & 15;
    const int row = rows[q];
    const int rl  = wid * 4 + q;          // block-row index

    float tq[16];
    #pragma unroll
    for (int i = 0; i < 16; ++i)
        tq[i] = tot[i >> 2][rl * 4 + (i & 3)];

    float l1x_out = tq[15] + b1[e * 16 + 15];

    float h1v[30];
    #pragma unroll
    for (int i = 0; i < 15; ++i) {
        float v = tq[i] + b1[e * 16 + i];
        float sq = v * v * SQCORR;
        h1v[i]      = fminf(fmaxf(sq, 0.0f), 1.0f);
        h1v[i + 15] = fminf(fmaxf(v,  0.0f), 1.0f);
    }

    float s0 = b2[e * 32 + j];
    float s1 = b2[e * 32 + 16 + j];
    const float* w2e = w2 + (size_t)e * 32 * 30;
    #pragma unroll
    for (int i = 0; i < 30; ++i) {
        s0 = fmaf(h1v[i], w2e[j * 30 + i], s0);
        s1 = fmaf(h1v[i], w2e[(16 + j) * 30 + i], s1);
    }
    s0 = fminf(fmaxf(s0, 0.0f), 1.0f);
    s1 = fminf(fmaxf(s1, 0.0f), 1.0f);

    float p = s0 * w3[e * 32 + j] + s1 * w3[e * 32 + 16 + j];
    #pragma unroll
    for (int m = 8; m >= 1; m >>= 1) p += __shfl_xor(p, m, 64);

    if (j == 0 && row >= 0) out[row] = p + b3[e] + l1x_out;
}

extern "C" void kernel_launch(void* const* d_in, const int* in_sizes, int n_in,
                              void* d_out, int out_size, void* d_ws, size_t ws_size,
                              hipStream_t stream) {
    const float* x       = (const float*)d_in[0];
    const int*   routing = (const int*)d_in[1];
    const float* w1      = (const float*)d_in[2];
    const float* b1      = (const float*)d_in[3];
    const float* w2      = (const float*)d_in[4];
    const float* b2      = (const float*)d_in[5];
    const float* w3      = (const float*)d_in[6];
    const float* b3      = (const float*)d_in[7];
    float* out = (float*)d_out;
    int*   ws  = (int*)d_ws;

    hist_k<<<NBLK_SORT, 256, 0, stream>>>(routing, ws);
    scan_k<<<1, 128, 0, stream>>>(ws);
    scatter_k<<<NBLK_SORT, 256, 0, stream>>>(routing, ws);
    // MEASUREMENT: double launch (idempotent). main = (total - prep) / 2;
    // both mains surface in rocprof top-5 with FETCH/VALUBusy/VGPR.
    moe_main_k<<<NBLK_MAIN, 256, 0, stream>>>(x, ws, w1, b1, w2, b2, w3, b3, out);
    moe_main_k<<<NBLK_MAIN, 256, 0, stream>>>(x, ws, w1, b1, w2, b2, w3, b3, out);
}

// Round 16
// 111.095 us; speedup vs baseline: 1.9430x; 1.9430x over previous
//
#include <hip/hip_runtime.h>

// Problem constants
#define NEXP   8
#define L1DIM  3072
#define BATCH  32768
#define SQCORR (127.0f / 128.0f)
#define CHUNK  256                    // floats per row per K-step
#define NCHUNK (L1DIM / CHUNK)        // 12

// Workspace layout (int units). Fixed per-expert segments; cursors padded
// to 64B lines. init_k resets cursors every call (ws is not re-poisoned
// between replays, so state must be re-derived deterministically).
#define CUR_STRIDE  16
#define WS_CURSORS  0                       // [8 * CUR_STRIDE]
#define WS_SORTED   (NEXP * CUR_STRIDE)     // [8*BATCH]
#define NBLK_SORT   (BATCH / 256)           // 128
#define BLK_PER_E   (BATCH / 16)            // 2048
#define NBLK_MAIN   (NEXP * BLK_PER_E)      // 16384 (most early-exit)

__global__ void init_k(int* ws) {
    if (threadIdx.x < NEXP)
        ws[WS_CURSORS + threadIdx.x * CUR_STRIDE] = threadIdx.x * BATCH;
}

// Block-aggregated scatter into fixed expert segments: LDS ranks + 8 global
// atomics per block (padded cursor lines). Order within a segment is
// arbitrary — per-row math is placement-invariant, so output stays
// deterministic (R15 proved ascending order buys nothing: expert rows are
// a random 1/8 subsample, ~96KB apart regardless of order).
__global__ void scatter_k(const int* __restrict__ routing, int* ws) {
    __shared__ int h[NEXP];
    __shared__ int base[NEXP];
    if (threadIdx.x < NEXP) h[threadIdx.x] = 0;
    __syncthreads();
    int i = blockIdx.x * 256 + threadIdx.x;
    int e = routing[i];
    int rank = atomicAdd(&h[e], 1);
    __syncthreads();
    if (threadIdx.x < NEXP)
        base[threadIdx.x] =
            atomicAdd(&ws[WS_CURSORS + threadIdx.x * CUR_STRIDE], h[threadIdx.x]);
    __syncthreads();
    ws[WS_SORTED + base[e] + rank] = i;
}

// async 16B global -> LDS copy (per-lane global src, wave-linear LDS dest)
__device__ __forceinline__ void lds_cp16(void* lds, const void* g) {
    __builtin_amdgcn_global_load_lds(
        (const __attribute__((address_space(1))) void*)g,
        (__attribute__((address_space(3))) void*)lds, 16, 0, 0);
}

// Main fused kernel — BEST-KNOWN CONFIG (R12 structure, R14 launch bounds).
//   - o-split: wave w owns outputs [4w,4w+4) for all 16 block rows ->
//     16 wv + 16 gll = 32 VMEM instrs/block-chunk (the R6->R12 2.5x cut,
//     the only lever with measured causal power: ~13.5cy/VMEM-instr).
//   - x: 3-deep LDS pipeline via global_load_lds, issue distance 2.
//   - w1: same-chunk register loads (reg-dbuf proved neutral in R14).
//   - __launch_bounds__(256,1): VGPR cap 256 -> no spill (R13: (256,3)
//     caps at 84 and spills 328MB). LDS 49KB binds occupancy: 3 blk/CU.
// Cross-round evidence says main ~96us ~= DRAM-efficiency cap for a
// 1KB-granule random-stride gather of 403MB (65-70% of 6.3TB/s).
//
// Per-wave vmcnt FIFO: chunk t top: outstanding = [x(t):4, x(t+1):4]
// (chunk t-1's wv-consume wait vmcnt(8-ish) already drained older).
// vmcnt(4): x(t) resident, x(t+1) kept in flight. Barrier -> block-wide.
__global__ __launch_bounds__(256, 1) void moe_main_k(
        const float* __restrict__ x, const int* __restrict__ ws,
        const float* __restrict__ w1, const float* __restrict__ b1,
        const float* __restrict__ w2, const float* __restrict__ b2,
        const float* __restrict__ w3, const float* __restrict__ b3,
        float* __restrict__ out) {
    __shared__ float xs[3][16][CHUNK];    // 48 KB
    __shared__ float tot[4][64];          // 49 KB total -> 3 blocks/CU

    const int e   = blockIdx.x % NEXP;
    const int b16 = (blockIdx.x / NEXP) * 16;
    const int n   = ws[WS_CURSORS + e * CUR_STRIDE] - e * BATCH;  // count_e
    if (b16 >= n) return;    // uniform: all 4 waves exit before any barrier

    const int tid  = threadIdx.x;
    const int wid  = tid >> 6;
    const int lane = tid & 63;
    const int r0   = wid * 4;             // rows this wave STAGES
    const int loff = lane * 4;

    int rows[4];
    const float* xp[4];
    #pragma unroll
    for (int q = 0; q < 4; ++q) {
        int s = b16 + r0 + q;
        rows[q] = (s < n) ? ws[WS_SORTED + e * BATCH + s] : -1;
        int r = rows[q] < 0 ? 0 : rows[q];
        xp[q] = x + (size_t)r * L1DIM;
    }
    // this wave's 4 output rows of w1[e]: o = wid*4 + oo
    const float* w1e = w1 + ((size_t)e * 16 + wid * 4) * L1DIM + loff;

    auto issue_x = [&](int t) {
        const int b = t % 3;
        const int koff = t * CHUNK + loff;
        #pragma unroll
        for (int q = 0; q < 4; ++q)
            lds_cp16(&xs[b][r0 + q][loff], xp[q] + koff);
    };

    float acc[64];                        // acc[r*4 + oo]
    #pragma unroll
    for (int k = 0; k < 64; ++k) acc[k] = 0.0f;

    issue_x(0);
    issue_x(1);

    #pragma unroll 1
    for (int t = 0; t < NCHUNK; ++t) {
        const int xb = t % 3;
        // own x(t) drained (keep x(t+1) in flight), then block-wide visible
        asm volatile("s_waitcnt vmcnt(4)" ::: "memory");
        __builtin_amdgcn_s_barrier();
        __builtin_amdgcn_sched_barrier(0);

        // this wave's 4 w1 vectors for chunk t (only the o-slice it owns)
        float4 wv[4];
        #pragma unroll
        for (int oo = 0; oo < 4; ++oo)
            wv[oo] = *(const float4*)(w1e + t * CHUNK + (size_t)oo * L1DIM);

        __builtin_amdgcn_sched_barrier(0);
        if (t + 2 < NCHUNK) issue_x(t + 2);
        __builtin_amdgcn_sched_barrier(0);

        // all 16 block rows x this wave's 4 outputs
        #pragma unroll
        for (int rg = 0; rg < 4; ++rg) {
            float4 xv[4];
            #pragma unroll
            for (int rr = 0; rr < 4; ++rr)
                xv[rr] = *(const float4*)&xs[xb][rg * 4 + rr][loff];
            #pragma unroll
            for (int oo = 0; oo < 4; ++oo) {
                #pragma unroll
                for (int rr = 0; rr < 4; ++rr) {
                    const int v = (rg * 4 + rr) * 4 + oo;
                    float a = acc[v];
                    a = fmaf(xv[rr].x, wv[oo].x, a);
                    a = fmaf(xv[rr].y, wv[oo].y, a);
                    a = fmaf(xv[rr].z, wv[oo].z, a);
                    a = fmaf(xv[rr].w, wv[oo].w, a);
                    acc[v] = a;
                }
            }
        }
    }

    // Reduce-scatter butterfly: lane l ends with total of value idx l,
    // where idx v = block_row(v>>2)*4 + oo; this wave's o = wid*4+oo.
    #pragma unroll
    for (int s = 0; s < 6; ++s) {
        const int mask = 32 >> s;
        const bool hi = (lane & mask) != 0;
        #pragma unroll
        for (int k = 0; k < 32; ++k) {
            if (k >= mask) break;
            float give = hi ? acc[k] : acc[k + mask];
            float got  = __shfl_xor(give, mask, 64);
            float keep = hi ? acc[k + mask] : acc[k];
            acc[k] = keep + got;
        }
    }

    tot[wid][lane] = acc[0];   // tot[w][R*4+oo] = out (R, o=w*4+oo)
    __syncthreads();

    // Epilogue: wave wid handles block rows wid*4+q (== its rows[q]).
    const int q = lane >> 4;
    const int j = lane & 15;
    const int row = rows[q];
    const int rl  = wid * 4 + q;          // block-row index

    float tq[16];
    #pragma unroll
    for (int i = 0; i < 16; ++i)
        tq[i] = tot[i >> 2][rl * 4 + (i & 3)];

    float l1x_out = tq[15] + b1[e * 16 + 15];

    float h1v[30];
    #pragma unroll
    for (int i = 0; i < 15; ++i) {
        float v = tq[i] + b1[e * 16 + i];
        float sq = v * v * SQCORR;
        h1v[i]      = fminf(fmaxf(sq, 0.0f), 1.0f);
        h1v[i + 15] = fminf(fmaxf(v,  0.0f), 1.0f);
    }

    float s0 = b2[e * 32 + j];
    float s1 = b2[e * 32 + 16 + j];
    const float* w2e = w2 + (size_t)e * 32 * 30;
    #pragma unroll
    for (int i = 0; i < 30; ++i) {
        s0 = fmaf(h1v[i], w2e[j * 30 + i], s0);
        s1 = fmaf(h1v[i], w2e[(16 + j) * 30 + i], s1);
    }
    s0 = fminf(fmaxf(s0, 0.0f), 1.0f);
    s1 = fminf(fmaxf(s1, 0.0f), 1.0f);

    float p = s0 * w3[e * 32 + j] + s1 * w3[e * 32 + 16 + j];
    #pragma unroll
    for (int m = 8; m >= 1; m >>= 1) p += __shfl_xor(p, m, 64);

    if (j == 0 && row >= 0) out[row] = p + b3[e] + l1x_out;
}

extern "C" void kernel_launch(void* const* d_in, const int* in_sizes, int n_in,
                              void* d_out, int out_size, void* d_ws, size_t ws_size,
                              hipStream_t stream) {
    const float* x       = (const float*)d_in[0];
    const int*   routing = (const int*)d_in[1];
    const float* w1      = (const float*)d_in[2];
    const float* b1      = (const float*)d_in[3];
    const float* w2      = (const float*)d_in[4];
    const float* b2      = (const float*)d_in[5];
    const float* w3      = (const float*)d_in[6];
    const float* b3      = (const float*)d_in[7];
    float* out = (float*)d_out;
    int*   ws  = (int*)d_ws;

    init_k<<<1, 64, 0, stream>>>(ws);
    scatter_k<<<NBLK_SORT, 256, 0, stream>>>(routing, ws);
    moe_main_k<<<NBLK_MAIN, 256, 0, stream>>>(x, ws, w1, b1, w2, b2, w3, b3, out);
}

// Round 17
// 110.402 us; speedup vs baseline: 1.9552x; 1.0063x over previous
//
#include <hip/hip_runtime.h>

// Problem constants
#define NEXP   8
#define L1DIM  3072
#define BATCH  32768
#define SQCORR (127.0f / 128.0f)
#define CHUNK  256                    // floats per row per K-step
#define NCHUNK (L1DIM / CHUNK)        // 12

// Workspace layout (int units). Fixed per-expert segments; cursors padded
// to 64B lines. init_k resets cursors every call (ws is not re-poisoned
// between replays, so state must be re-derived deterministically).
#define CUR_STRIDE  16
#define WS_CURSORS  0                       // [8 * CUR_STRIDE]
#define WS_SORTED   (NEXP * CUR_STRIDE)     // [8*BATCH]
#define NBLK_SORT   (BATCH / 256)           // 128
#define BLK_PER_E   (BATCH / 16)            // 2048
#define NBLK_MAIN   (NEXP * BLK_PER_E)      // 16384 (most early-exit)

__global__ void init_k(int* ws) {
    if (threadIdx.x < NEXP)
        ws[WS_CURSORS + threadIdx.x * CUR_STRIDE] = threadIdx.x * BATCH;
}

// Block-aggregated scatter into fixed expert segments: LDS ranks + 8 global
// atomics per block (padded cursor lines). Order within a segment is
// arbitrary — per-row math is placement-invariant, so output stays
// deterministic (R15 proved ascending order buys nothing: expert rows are
// a random 1/8 subsample, ~96KB apart regardless of order).
__global__ void scatter_k(const int* __restrict__ routing, int* ws) {
    __shared__ int h[NEXP];
    __shared__ int base[NEXP];
    if (threadIdx.x < NEXP) h[threadIdx.x] = 0;
    __syncthreads();
    int i = blockIdx.x * 256 + threadIdx.x;
    int e = routing[i];
    int rank = atomicAdd(&h[e], 1);
    __syncthreads();
    if (threadIdx.x < NEXP)
        base[threadIdx.x] =
            atomicAdd(&ws[WS_CURSORS + threadIdx.x * CUR_STRIDE], h[threadIdx.x]);
    __syncthreads();
    ws[WS_SORTED + base[e] + rank] = i;
}

// async 16B global -> LDS copy (per-lane global src, wave-linear LDS dest)
__device__ __forceinline__ void lds_cp16(void* lds, const void* g) {
    __builtin_amdgcn_global_load_lds(
        (const __attribute__((address_space(1))) void*)g,
        (__attribute__((address_space(3))) void*)lds, 16, 0, 0);
}

// Main fused kernel — BEST-KNOWN CONFIG (R12 structure, R14 launch bounds).
//   - o-split: wave w owns outputs [4w,4w+4) for all 16 block rows ->
//     16 wv + 16 gll = 32 VMEM instrs/block-chunk (the R6->R12 2.5x cut,
//     the only lever with measured causal power: ~13.5cy/VMEM-instr).
//   - x: 3-deep LDS pipeline via global_load_lds, issue distance 2.
//   - w1: same-chunk register loads (reg-dbuf proved neutral in R14).
//   - __launch_bounds__(256,1): VGPR cap 256 -> no spill (R13: (256,3)
//     caps at 84 and spills 328MB). LDS 49KB binds occupancy: 3 blk/CU.
// Cross-round evidence says main ~96us ~= DRAM-efficiency cap for a
// 1KB-granule random-stride gather of 403MB (65-70% of 6.3TB/s).
//
// Per-wave vmcnt FIFO: chunk t top: outstanding = [x(t):4, x(t+1):4]
// (chunk t-1's wv-consume wait vmcnt(8-ish) already drained older).
// vmcnt(4): x(t) resident, x(t+1) kept in flight. Barrier -> block-wide.
__global__ __launch_bounds__(256, 1) void moe_main_k(
        const float* __restrict__ x, const int* __restrict__ ws,
        const float* __restrict__ w1, const float* __restrict__ b1,
        const float* __restrict__ w2, const float* __restrict__ b2,
        const float* __restrict__ w3, const float* __restrict__ b3,
        float* __restrict__ out) {
    __shared__ float xs[3][16][CHUNK];    // 48 KB
    __shared__ float tot[4][64];          // 49 KB total -> 3 blocks/CU

    const int e   = blockIdx.x % NEXP;
    const int b16 = (blockIdx.x / NEXP) * 16;
    const int n   = ws[WS_CURSORS + e * CUR_STRIDE] - e * BATCH;  // count_e
    if (b16 >= n) return;    // uniform: all 4 waves exit before any barrier

    const int tid  = threadIdx.x;
    const int wid  = tid >> 6;
    const int lane = tid & 63;
    const int r0   = wid * 4;             // rows this wave STAGES
    const int loff = lane * 4;

    int rows[4];
    const float* xp[4];
    #pragma unroll
    for (int q = 0; q < 4; ++q) {
        int s = b16 + r0 + q;
        rows[q] = (s < n) ? ws[WS_SORTED + e * BATCH + s] : -1;
        int r = rows[q] < 0 ? 0 : rows[q];
        xp[q] = x + (size_t)r * L1DIM;
    }
    // this wave's 4 output rows of w1[e]: o = wid*4 + oo
    const float* w1e = w1 + ((size_t)e * 16 + wid * 4) * L1DIM + loff;

    auto issue_x = [&](int t) {
        const int b = t % 3;
        const int koff = t * CHUNK + loff;
        #pragma unroll
        for (int q = 0; q < 4; ++q)
            lds_cp16(&xs[b][r0 + q][loff], xp[q] + koff);
    };

    float acc[64];                        // acc[r*4 + oo]
    #pragma unroll
    for (int k = 0; k < 64; ++k) acc[k] = 0.0f;

    issue_x(0);
    issue_x(1);

    #pragma unroll 1
    for (int t = 0; t < NCHUNK; ++t) {
        const int xb = t % 3;
        // own x(t) drained (keep x(t+1) in flight), then block-wide visible
        asm volatile("s_waitcnt vmcnt(4)" ::: "memory");
        __builtin_amdgcn_s_barrier();
        __builtin_amdgcn_sched_barrier(0);

        // this wave's 4 w1 vectors for chunk t (only the o-slice it owns)
        float4 wv[4];
        #pragma unroll
        for (int oo = 0; oo < 4; ++oo)
            wv[oo] = *(const float4*)(w1e + t * CHUNK + (size_t)oo * L1DIM);

        __builtin_amdgcn_sched_barrier(0);
        if (t + 2 < NCHUNK) issue_x(t + 2);
        __builtin_amdgcn_sched_barrier(0);

        // all 16 block rows x this wave's 4 outputs
        #pragma unroll
        for (int rg = 0; rg < 4; ++rg) {
            float4 xv[4];
            #pragma unroll
            for (int rr = 0; rr < 4; ++rr)
                xv[rr] = *(const float4*)&xs[xb][rg * 4 + rr][loff];
            #pragma unroll
            for (int oo = 0; oo < 4; ++oo) {
                #pragma unroll
                for (int rr = 0; rr < 4; ++rr) {
                    const int v = (rg * 4 + rr) * 4 + oo;
                    float a = acc[v];
                    a = fmaf(xv[rr].x, wv[oo].x, a);
                    a = fmaf(xv[rr].y, wv[oo].y, a);
                    a = fmaf(xv[rr].z, wv[oo].z, a);
                    a = fmaf(xv[rr].w, wv[oo].w, a);
                    acc[v] = a;
                }
            }
        }
    }

    // Reduce-scatter butterfly: lane l ends with total of value idx l,
    // where idx v = block_row(v>>2)*4 + oo; this wave's o = wid*4+oo.
    #pragma unroll
    for (int s = 0; s < 6; ++s) {
        const int mask = 32 >> s;
        const bool hi = (lane & mask) != 0;
        #pragma unroll
        for (int k = 0; k < 32; ++k) {
            if (k >= mask) break;
            float give = hi ? acc[k] : acc[k + mask];
            float got  = __shfl_xor(give, mask, 64);
            float keep = hi ? acc[k + mask] : acc[k];
            acc[k] = keep + got;
        }
    }

    tot[wid][lane] = acc[0];   // tot[w][R*4+oo] = out (R, o=w*4+oo)
    __syncthreads();

    // Epilogue: wave wid handles block rows wid*4+q (== its rows[q]).
    const int q = lane >> 4;
    const int j = lane & 15;
    const int row = rows[q];
    const int rl  = wid * 4 + q;          // block-row index

    float tq[16];
    #pragma unroll
    for (int i = 0; i < 16; ++i)
        tq[i] = tot[i >> 2][rl * 4 + (i & 3)];

    float l1x_out = tq[15] + b1[e * 16 + 15];

    float h1v[30];
    #pragma unroll
    for (int i = 0; i < 15; ++i) {
        float v = tq[i] + b1[e * 16 + i];
        float sq = v * v * SQCORR;
        h1v[i]      = fminf(fmaxf(sq, 0.0f), 1.0f);
        h1v[i + 15] = fminf(fmaxf(v,  0.0f), 1.0f);
    }

    float s0 = b2[e * 32 + j];
    float s1 = b2[e * 32 + 16 + j];
    const float* w2e = w2 + (size_t)e * 32 * 30;
    #pragma unroll
    for (int i = 0; i < 30; ++i) {
        s0 = fmaf(h1v[i], w2e[j * 30 + i], s0);
        s1 = fmaf(h1v[i], w2e[(16 + j) * 30 + i], s1);
    }
    s0 = fminf(fmaxf(s0, 0.0f), 1.0f);
    s1 = fminf(fmaxf(s1, 0.0f), 1.0f);

    float p = s0 * w3[e * 32 + j] + s1 * w3[e * 32 + 16 + j];
    #pragma unroll
    for (int m = 8; m >= 1; m >>= 1) p += __shfl_xor(p, m, 64);

    if (j == 0 && row >= 0) out[row] = p + b3[e] + l1x_out;
}

extern "C" void kernel_launch(void* const* d_in, const int* in_sizes, int n_in,
                              void* d_out, int out_size, void* d_ws, size_t ws_size,
                              hipStream_t stream) {
    const float* x       = (const float*)d_in[0];
    const int*   routing = (const int*)d_in[1];
    const float* w1      = (const float*)d_in[2];
    const float* b1      = (const float*)d_in[3];
    const float* w2      = (const float*)d_in[4];
    const float* b2      = (const float*)d_in[5];
    const float* w3      = (const float*)d_in[6];
    const float* b3      = (const float*)d_in[7];
    float* out = (float*)d_out;
    int*   ws  = (int*)d_ws;

    init_k<<<1, 64, 0, stream>>>(ws);
    scatter_k<<<NBLK_SORT, 256, 0, stream>>>(routing, ws);
    moe_main_k<<<NBLK_MAIN, 256, 0, stream>>>(x, ws, w1, b1, w2, b2, w3, b3, out);
}